// Round 20
// baseline (189.718 us; speedup 1.0000x reference)
//
#include <hip/hip_runtime.h>
#include <hip/hip_bf16.h>

#define B_ 128
#define S_ 48
#define W_ 12
#define V_ 32000
#define SYM_ 128
#define H_ 256
#define E_ 48
#define R_ 24

typedef float f32x4 __attribute__((ext_vector_type(4)));

__device__ __forceinline__ float4 fma4(float s, float4 w, float4 a) {
    a.x = fmaf(s, w.x, a.x); a.y = fmaf(s, w.y, a.y);
    a.z = fmaf(s, w.z, a.z); a.w = fmaf(s, w.w, a.w);
    return a;
}
__device__ __forceinline__ f32x4 fmabc(float s, f32x4 w, f32x4 a) {
    f32x4 sv = {s, s, s, s};
    return __builtin_elementwise_fma(sv, w, a);
}

// global -> LDS async copy, 16 B per lane
__device__ __forceinline__ void gl_lds16(const float* g, float* l) {
    __builtin_amdgcn_global_load_lds(
        (const __attribute__((address_space(1))) void*)g,
        (__attribute__((address_space(3))) void*)l, 16, 0, 0);
}

__device__ __forceinline__ float dot48(const float* A, const float* Bp) {
    const float4* a = reinterpret_cast<const float4*>(A);
    const float4* b4 = reinterpret_cast<const float4*>(Bp);
    float4 acc = {0.f, 0.f, 0.f, 0.f};
#pragma unroll
    for (int i = 0; i < 12; ++i) {
        float4 x = a[i], y = b4[i];
        acc.x = fmaf(x.x, y.x, acc.x); acc.y = fmaf(x.y, y.y, acc.y);
        acc.z = fmaf(x.z, y.z, acc.z); acc.w = fmaf(x.w, y.w, acc.w);
    }
    return (acc.x + acc.y) + (acc.z + acc.w);
}
__device__ __forceinline__ float dot24(const float* A, const float* Bp) {
    const float4* a = reinterpret_cast<const float4*>(A);
    const float4* b4 = reinterpret_cast<const float4*>(Bp);
    float4 acc = {0.f, 0.f, 0.f, 0.f};
#pragma unroll
    for (int i = 0; i < 6; ++i) {
        float4 x = a[i], y = b4[i];
        acc.x = fmaf(x.x, y.x, acc.x); acc.y = fmaf(x.y, y.y, acc.y);
        acc.z = fmaf(x.z, y.z, acc.z); acc.w = fmaf(x.w, y.w, acc.w);
    }
    return (acc.x + acc.y) + (acc.z + acc.w);
}

// ---------------------------------------------------------------------------
// Kernel 1: ssum / qsum
// ---------------------------------------------------------------------------
__global__ __launch_bounds__(128) void ssum_kernel(
    const int* __restrict__ story, const int* __restrict__ query,
    const float* __restrict__ we, const float* __restrict__ pe,
    float* __restrict__ ssum, float* __restrict__ qsum)
{
    int i = blockIdx.x;
    int c = threadIdx.x;
    const int* idxp;
    float* outp;
    if (i < B_ * S_) {
        idxp = story + (size_t)i * W_;
        outp = ssum + (size_t)i * SYM_;
    } else {
        int b = i - B_ * S_;
        idxp = query + (size_t)b * W_;
        outp = qsum + (size_t)b * SYM_;
    }
    float acc = 0.f;
#pragma unroll
    for (int w = 0; w < W_; ++w) {
        int id = idxp[w];
        acc = fmaf(we[(size_t)id * SYM_ + c], pe[w * SYM_ + c], acc);
    }
    outp[c] = acc;
}

// ---------------------------------------------------------------------------
// Kernel 2 (r20): r18 structure with the W ring deepened 3 -> 6 slots,
// staged 5 chunks ahead (lead ~900 cyc >= HBM latency), per-iter counted
// vmcnt(8). x via wave-uniform s_loads (r18 path, best measured).
// Slot (c+5)%6 reuse is safe: last computed at iter c-1, and this iter's
// barrier orders all waves past that compute.
// ---------------------------------------------------------------------------
template<int NQ, int TMv>
__device__ __forceinline__ void mlp_layer2(
    int t, int row0, const float4* hs4, const float* __restrict__ W2,
    const float* __restrict__ b2, float* __restrict__ out)
{
    const float4* W2_4 = reinterpret_cast<const float4*>(W2);  // [256][NQ]
    for (int idx = t; idx < TMv * NQ; idx += 256) {
        int row = idx / NQ, q = idx - row * NQ;
        float4 cw0 = W2_4[0 * NQ + q];
        float4 cw1 = W2_4[1 * NQ + q];
        float4 cw2 = W2_4[2 * NQ + q];
        float4 cw3 = W2_4[3 * NQ + q];
        float4 a = {0, 0, 0, 0};
#pragma unroll 1
        for (int k4 = 0; k4 < H_ / 4 - 1; ++k4) {
            float4 nw0 = W2_4[(size_t)(4 * k4 + 4) * NQ + q];
            float4 nw1 = W2_4[(size_t)(4 * k4 + 5) * NQ + q];
            float4 nw2 = W2_4[(size_t)(4 * k4 + 6) * NQ + q];
            float4 nw3 = W2_4[(size_t)(4 * k4 + 7) * NQ + q];
            float4 h = hs4[row * 65 + k4];
            a = fma4(h.x, cw0, fma4(h.y, cw1, fma4(h.z, cw2, fma4(h.w, cw3, a))));
            cw0 = nw0; cw1 = nw1; cw2 = nw2; cw3 = nw3;
        }
        {
            float4 h = hs4[row * 65 + (H_ / 4 - 1)];
            a = fma4(h.x, cw0, fma4(h.y, cw1, fma4(h.z, cw2, fma4(h.w, cw3, a))));
        }
        float4 bv = reinterpret_cast<const float4*>(b2)[q];
        float4 o;
        o.x = tanhf(a.x + bv.x); o.y = tanhf(a.y + bv.y);
        o.z = tanhf(a.z + bv.z); o.w = tanhf(a.w + bv.w);
        reinterpret_cast<float4*>(out + (size_t)(row0 + row) * (NQ * 4))[q] = o;
    }
}

template<int ROWS>
__global__ __launch_bounds__(256) void mlp_kernel(
    const float* __restrict__ x, int M,
    const float* __restrict__ W1e, const float* __restrict__ b1e,
    const float* __restrict__ W2e, const float* __restrict__ b2e,
    int nE,
    const float* __restrict__ W1r, const float* __restrict__ b1r,
    const float* __restrict__ W2r, const float* __restrict__ b2r,
    float* __restrict__ outE,   // [nE][M][48]
    float* __restrict__ outR)   // [nR][M][24]
{
    constexpr int TMv = ROWS * 4;
    // LDS pool: max(6-slot ring = 12288 floats, hs = TMv*65*4 floats)
    constexpr int POOLF = (12288 > TMv * 65 * 4) ? 12288 : TMv * 65 * 4;

    int m = blockIdx.y;
    int row0 = blockIdx.x * TMv;
    const float *W1, *b1, *W2, *b2;
    float* out;
    int OUT;
    if (m < nE) {
        W1 = W1e + (size_t)m * SYM_ * H_;
        b1 = b1e + (size_t)m * H_;
        W2 = W2e + (size_t)m * H_ * E_;
        b2 = b2e + (size_t)m * E_;
        out = outE + (size_t)m * M * E_;
        OUT = E_;
    } else {
        int mr = m - nE;
        W1 = W1r + (size_t)mr * SYM_ * H_;
        b1 = b1r + (size_t)mr * H_;
        W2 = W2r + (size_t)mr * H_ * R_;
        b2 = b2r + (size_t)mr * R_;
        out = outR + (size_t)mr * M * R_;
        OUT = R_;
    }

    const int t = threadIdx.x;
    const int wv = t >> 6;      // wave owns rows ROWS*wv .. ROWS*wv+ROWS-1
    const int l = t & 63;       // lane = col-quad

    __shared__ __align__(16) float pool[POOLF];
    float* wlds = pool;
    float4* hs4 = reinterpret_cast<float4*>(pool);

    // wave-uniform x row base -> SGPR -> x reads are s_loads
    const int xoff = __builtin_amdgcn_readfirstlane((row0 + ROWS * wv) * SYM_);
    const float* xw = x + xoff;

#define STAGE(c) { \
    const float* gsrc = W1 + (c) * 2048 + t * 4; \
    float* dst = wlds + ((c) % 6) * 2048 + wv * 256; \
    gl_lds16(gsrc, dst); \
    gl_lds16(gsrc + 1024, dst + 1024); }

#define CHUNK_COMPUTE(c_) { \
    const float* wl = wlds + ((c_) % 6) * 2048; \
    const float* xc = xw + (c_) * 8; \
    _Pragma("unroll") \
    for (int k = 0; k < 8; ++k) { \
        f32x4 w4 = *reinterpret_cast<const f32x4*>(wl + k * 256 + l * 4); \
        A0 = fmabc(xc[0 * SYM_ + k], w4, A0); \
        A1 = fmabc(xc[1 * SYM_ + k], w4, A1); \
        A2 = fmabc(xc[2 * SYM_ + k], w4, A2); \
        A3 = fmabc(xc[3 * SYM_ + k], w4, A3); \
        A4 = fmabc(xc[4 * SYM_ + k], w4, A4); \
        A5 = fmabc(xc[5 * SYM_ + k], w4, A5); \
        if constexpr (ROWS == 8) { \
            A6 = fmabc(xc[6 * SYM_ + k], w4, A6); \
            A7 = fmabc(xc[7 * SYM_ + k], w4, A7); \
        } \
    } }

    f32x4 A0 = {0.f, 0.f, 0.f, 0.f};
    f32x4 A1 = A0, A2 = A0, A3 = A0, A4 = A0, A5 = A0, A6 = A0, A7 = A0;

    // prologue: stage 5 chunks ahead (10 gl_lds ops in flight)
    STAGE(0) STAGE(1) STAGE(2) STAGE(3) STAGE(4)

#pragma unroll 1
    for (int c = 0; c < 16; ++c) {
        // chunk c's 2 ops retired; chunks c+1..c+4 (8 ops) still in flight
        asm volatile("s_waitcnt vmcnt(8)" ::: "memory");
        __builtin_amdgcn_s_barrier();
        if (c + 5 < 16) STAGE(c + 5)
        CHUNK_COMPUTE(c)
    }
#undef CHUNK_COMPUTE
#undef STAGE

    __syncthreads();   // ring reads done before h overwrites pool

    {
        float4 bb = reinterpret_cast<const float4*>(b1)[l];
        float4 v;
#define H1ROW(i, AR) \
        v.x = tanhf(AR[0] + bb.x); v.y = tanhf(AR[1] + bb.y); \
        v.z = tanhf(AR[2] + bb.z); v.w = tanhf(AR[3] + bb.w); \
        hs4[(ROWS * wv + (i)) * 65 + l] = v;
        H1ROW(0, A0) H1ROW(1, A1) H1ROW(2, A2)
        H1ROW(3, A3) H1ROW(4, A4) H1ROW(5, A5)
        if constexpr (ROWS == 8) {
            H1ROW(6, A6) H1ROW(7, A7)
        }
#undef H1ROW
    }
    __syncthreads();

    if (OUT == E_) mlp_layer2<12, TMv>(t, row0, hs4, W2, b2, out);
    else           mlp_layer2<6, TMv>(t, row0, hs4, W2, b2, out);
}

// ---------------------------------------------------------------------------
// Kernel 3: FUSED gram + rec (unchanged from r18).
// ---------------------------------------------------------------------------
__global__ __launch_bounds__(512) void gramrec_kernel(
    const float* __restrict__ eg,   // [2][B][48][48]
    const float* __restrict__ rg,   // [3][B][48][24]
    const float* __restrict__ qe1,  // [B][48]
    const float* __restrict__ qrr,  // [3][B][24]
    float* __restrict__ qg,         // [B][544]
    float* __restrict__ abcg)       // [B][3][48][48]
{
    const int b = blockIdx.x;
    const int half = blockIdx.y;
    const int f0 = half * 24;
    const int t = threadIdx.x;

    __shared__ __align__(16) float eL[2][48][52];
    __shared__ __align__(16) float rL[3][48][28];
    __shared__ __align__(16) float KL[1128 * 12];
    __shared__ float acc[3][48][24];
    __shared__ float abc[3][48][24];

    for (int i = t; i < 2 * 2304; i += 512) {
        int x = i / 2304, rem = i - x * 2304;
        eL[x][rem / 48][rem % 48] = eg[(size_t)x * B_ * 2304 + (size_t)b * 2304 + rem];
    }
    for (int i = t; i < 3 * 1152; i += 512) {
        int x = i / 1152, rem = i - x * 1152;
        rL[x][rem / 24][rem % 24] = rg[(size_t)x * B_ * 1152 + (size_t)b * 1152 + rem];
    }
    for (int i = t; i < 3 * 48 * 24; i += 512) ((float*)acc)[i] = 0.f;
    __syncthreads();

    for (int k = t; k < 1128; k += 512) {
        int s2 = (int)((1.0f + sqrtf(1.0f + 8.0f * (float)k)) * 0.5f);
        while (s2 * (s2 - 1) / 2 > k) --s2;
        while ((s2 + 1) * s2 / 2 <= k) ++s2;
        int sp = k - s2 * (s2 - 1) / 2;

        float G11 = dot48(&eL[0][s2][0], &eL[0][sp][0]);
        float G12 = dot48(&eL[0][s2][0], &eL[1][sp][0]);
        float G21 = dot48(&eL[1][s2][0], &eL[0][sp][0]);
        float G22 = dot48(&eL[1][s2][0], &eL[1][sp][0]);
        float R11 = dot24(&rL[0][s2][0], &rL[0][sp][0]);
        float R12 = dot24(&rL[0][s2][0], &rL[1][sp][0]);
        float R13 = dot24(&rL[0][s2][0], &rL[2][sp][0]);
        float R21 = dot24(&rL[1][s2][0], &rL[0][sp][0]);
        float R22 = dot24(&rL[1][s2][0], &rL[1][sp][0]);
        float R23 = dot24(&rL[1][s2][0], &rL[2][sp][0]);
        float R31 = dot24(&rL[2][s2][0], &rL[0][sp][0]);
        float R32 = dot24(&rL[2][s2][0], &rL[1][sp][0]);
        float R33 = dot24(&rL[2][s2][0], &rL[2][sp][0]);

        float* kp = KL + (size_t)k * 12;
        float4 o0 = {G11 * R11, G11 * R12, G12 * R13, G11 * R21};
        float4 o1 = {G11 * R22, G12 * R23, G21 * R31, G21 * R32};
        *reinterpret_cast<float4*>(kp)     = o0;
        *reinterpret_cast<float4*>(kp + 4) = o1;
        kp[8] = G22 * R33;
    }

    if (half == 0) {
        float* dst = qg + (size_t)b * 544;
        for (int j = t; j < 528; j += 512) {
            if (j < 96) {
                int x = j / 48, sp = j % 48;
                const float* q = qe1 + b * 48;
                const float* v = &eL[x][sp][0];
                float a = 0.f;
#pragma unroll
                for (int kk = 0; kk < 48; ++kk) a = fmaf(q[kk], v[kk], a);
                dst[j] = a;
            } else {
                int jj = j - 96;
                int c = jj / 144;
                int rem = jj - c * 144;
                int rj = rem / 48, sp = rem % 48;
                const float* q = qrr + ((size_t)c * B_ + b) * 24;
                const float* v = &rL[rj][sp][0];
                float a = 0.f;
#pragma unroll
                for (int kk = 0; kk < 24; ++kk) a = fmaf(q[kk], v[kk], a);
                dst[j] = a;
            }
        }
    }
    __syncthreads();

    for (int s = 0; s < 48; ++s) {
        if (t < 24) {
            float w = acc[0][s][t], m = acc[1][s][t], bh = acc[2][s][t];
            abc[0][s][t] = eL[1][s][f0 + t] - w;
            abc[1][s][t] = w - m;
            abc[2][s][t] = eL[0][s][f0 + t] - bh;
        }
        __syncthreads();
        const int items = (47 - s) * 24;
        for (int idx = t; idx < items; idx += 512) {
            int d = idx / 24;
            int fl = idx - d * 24;
            int s2 = s + 1 + d;
            const float* kp = KL + (size_t)(s2 * (s2 - 1) / 2 + s) * 12;
            float4 k0 = *reinterpret_cast<const float4*>(kp);
            float4 k1 = *reinterpret_cast<const float4*>(kp + 4);
            float  k8 = kp[8];
            float av = abc[0][s][fl], bv = abc[1][s][fl], cv = abc[2][s][fl];
            acc[0][s2][fl] = fmaf(k0.x, av, fmaf(k0.y, bv, fmaf(k0.z, cv, acc[0][s2][fl])));
            acc[1][s2][fl] = fmaf(k0.w, av, fmaf(k1.x, bv, fmaf(k1.y, cv, acc[1][s2][fl])));
            acc[2][s2][fl] = fmaf(k1.z, av, fmaf(k1.w, bv, fmaf(k8,   cv, acc[2][s2][fl])));
        }
        __syncthreads();
    }
    for (int i = t; i < 3 * 48 * 24; i += 512) {
        int x = i / (48 * 24);
        int rem = i - x * 48 * 24;
        int s = rem / 24, fl = rem % 24;
        abcg[(size_t)b * 6912 + (size_t)x * 2304 + s * 48 + f0 + fl] = abc[x][s][fl];
    }
}

// ---------------------------------------------------------------------------
// Kernel 4: inference from the decomposition (unchanged).
// ---------------------------------------------------------------------------
__global__ __launch_bounds__(256) void infer2_kernel(
    const float* __restrict__ abcg, const float* __restrict__ eg,
    const float* __restrict__ qgg,
    const float* __restrict__ ln_gain, const float* __restrict__ ln_bias,
    float* __restrict__ isum)
{
    const int b = blockIdx.x;
    const int t = threadIdx.x;
    __shared__ float abc[3][48][48];
    __shared__ __align__(16) float eL[2][48][52];
    __shared__ float qgL[544];
    __shared__ float alpha[3][48];
    __shared__ float gtmp[2][48];
    __shared__ float cur[48], xv[48], acc3[48];

    for (int i = t; i < 6912; i += 256) ((float*)abc)[i] = abcg[(size_t)b * 6912 + i];
    for (int i = t; i < 2 * 2304; i += 256) {
        int x = i / 2304, rem = i - x * 2304;
        eL[x][rem / 48][rem % 48] = eg[(size_t)x * B_ * 2304 + (size_t)b * 2304 + rem];
    }
    for (int i = t; i < 544; i += 256) qgL[i] = qgg[(size_t)b * 544 + i];
    if (t < 48) acc3[t] = 0.f;
    __syncthreads();

    for (int c = 0; c < 3; ++c) {
        if (c > 0) {
            for (int j = t; j < 96; j += 256) {
                int x = j / 48, sp = j % 48;
                const float* v = &eL[x][sp][0];
                float a = 0.f;
#pragma unroll
                for (int kk = 0; kk < 48; ++kk) a = fmaf(cur[kk], v[kk], a);
                gtmp[x][sp] = a;
            }
            __syncthreads();
        }
        if (t < 48) {
            float g1 = (c == 0) ? qgL[t] : gtmp[0][t];
            float g2 = (c == 0) ? qgL[48 + t] : gtmp[1][t];
            alpha[0][t] = g1 * qgL[96 + c * 144 + t];
            alpha[1][t] = g1 * qgL[96 + c * 144 + 48 + t];
            alpha[2][t] = g2 * qgL[96 + c * 144 + 96 + t];
        }
        __syncthreads();
        if (t < 48) {
            float p = 0.f;
            for (int sp = 0; sp < 48; ++sp) {
                p = fmaf(alpha[0][sp], abc[0][sp][t],
                    fmaf(alpha[1][sp], abc[1][sp][t],
                    fmaf(alpha[2][sp], abc[2][sp][t], p)));
            }
            xv[t] = p;
        }
        __syncthreads();
        if (t < 48) {
            float mu = 0.f;
#pragma unroll
            for (int jj = 0; jj < 48; ++jj) mu += xv[jj];
            mu *= (1.f / 48.f);
            float var = 0.f;
#pragma unroll
            for (int jj = 0; jj < 48; ++jj) { float d = xv[jj] - mu; var = fmaf(d, d, var); }
            var *= (1.f / 48.f);
            float inv = 1.f / sqrtf(var + 1e-6f);
            float o = ln_gain[c * 48 + t] * (xv[t] - mu) * inv + ln_bias[c * 48 + t];
            cur[t] = o;
            acc3[t] += o;
        }
        __syncthreads();
    }
    if (t < 48) isum[b * 48 + t] = acc3[t];
}

// ---------------------------------------------------------------------------
// Kernel 5: logits[b,v] = sum_e isum[b,e] * Z[e,v]
// ---------------------------------------------------------------------------
__global__ __launch_bounds__(256) void logits_kernel(
    const float* __restrict__ isum,
    const float* __restrict__ Z,
    float* __restrict__ out)
{
    int v = blockIdx.x * 256 + threadIdx.x;
    int b0 = blockIdx.y * (B_ / 4);
    float z[E_];
#pragma unroll
    for (int e = 0; e < E_; ++e) z[e] = Z[(size_t)e * V_ + v];
    for (int b = b0; b < b0 + B_ / 4; ++b) {
        float a = 0.f;
#pragma unroll
        for (int e = 0; e < E_; ++e) a = fmaf(isum[b * 48 + e], z[e], a);
        out[(size_t)b * V_ + v] = a;
    }
}

// ---------------------------------------------------------------------------
extern "C" void kernel_launch(void* const* d_in, const int* in_sizes, int n_in,
                              void* d_out, int out_size, void* d_ws, size_t ws_size,
                              hipStream_t stream) {
    const int* story  = (const int*)d_in[0];
    const int* query  = (const int*)d_in[1];
    const float* we   = (const float*)d_in[2];
    const float* pe   = (const float*)d_in[3];
    const float* Z    = (const float*)d_in[4];
    const float* ue_W1 = (const float*)d_in[5];
    const float* ue_b1 = (const float*)d_in[6];
    const float* ue_W2 = (const float*)d_in[7];
    const float* ue_b2 = (const float*)d_in[8];
    const float* ur_W1 = (const float*)d_in[9];
    const float* ur_b1 = (const float*)d_in[10];
    const float* ur_W2 = (const float*)d_in[11];
    const float* ur_b2 = (const float*)d_in[12];
    const float* ie_W1 = (const float*)d_in[13];
    const float* ie_b1 = (const float*)d_in[14];
    const float* ie_W2 = (const float*)d_in[15];
    const float* ie_b2 = (const float*)d_in[16];
    const float* ir_W1 = (const float*)d_in[17];
    const float* ir_b1 = (const float*)d_in[18];
    const float* ir_W2 = (const float*)d_in[19];
    const float* ir_b2 = (const float*)d_in[20];
    const float* ln_g  = (const float*)d_in[21];
    const float* ln_b  = (const float*)d_in[22];
    float* out = (float*)d_out;

    float* ws = (float*)d_ws;
    float* ssum = ws;                                   // 786432
    float* qsum = ssum + (size_t)B_ * S_ * SYM_;        // 16384
    float* eout = qsum + (size_t)B_ * SYM_;             // 589824
    float* rout = eout + (size_t)2 * B_ * S_ * E_;      // 442368
    float* qe1  = rout + (size_t)3 * B_ * S_ * R_;      // 6144
    float* qrr  = qe1 + (size_t)B_ * E_;                // 9216
    float* abcg = qrr + (size_t)3 * B_ * R_;            // 884736
    float* qg   = abcg + (size_t)B_ * 6912;             // 69632
    float* isum = qg + (size_t)B_ * 544;                // 6144

    ssum_kernel<<<B_ * S_ + B_, 128, 0, stream>>>(story, query, we, pe, ssum, qsum);

    // story MLPs: TM=24 -> grid 256 x 5 = 1280 blocks (exactly 5 per CU)
    mlp_kernel<6><<<dim3((B_ * S_) / 24, 5), 256, 0, stream>>>(
        ssum, B_ * S_, ue_W1, ue_b1, ue_W2, ue_b2, 2,
        ur_W1, ur_b1, ur_W2, ur_b2, eout, rout);

    // query MLPs: TM=32 (128 rows divisible)
    mlp_kernel<8><<<dim3(B_ / 32, 4), 256, 0, stream>>>(
        qsum, B_, ie_W1, ie_b1, ie_W2, ie_b2, 1,
        ir_W1, ir_b1, ir_W2, ir_b2, qe1, qrr);

    gramrec_kernel<<<dim3(B_, 2), 512, 0, stream>>>(eout, rout, qe1, qrr, qg, abcg);

    infer2_kernel<<<B_, 256, 0, stream>>>(abcg, eout, qg, ln_g, ln_b, isum);

    logits_kernel<<<dim3(V_ / 256, 4), 256, 0, stream>>>(isum, Z, out);
}

// Round 21
// 142.560 us; speedup vs baseline: 1.3308x; 1.3308x over previous
//
#include <hip/hip_runtime.h>
#include <hip/hip_bf16.h>

#define B_ 128
#define S_ 48
#define W_ 12
#define V_ 32000
#define SYM_ 128
#define H_ 256
#define E_ 48
#define R_ 24
#define ROWS 6
#define TMV 24

typedef float f32x4 __attribute__((ext_vector_type(4)));

__device__ __forceinline__ float4 fma4(float s, float4 w, float4 a) {
    a.x = fmaf(s, w.x, a.x); a.y = fmaf(s, w.y, a.y);
    a.z = fmaf(s, w.z, a.z); a.w = fmaf(s, w.w, a.w);
    return a;
}
__device__ __forceinline__ f32x4 fmabc(float s, f32x4 w, f32x4 a) {
    f32x4 sv = {s, s, s, s};
    return __builtin_elementwise_fma(sv, w, a);
}

// global -> LDS async copy, 16 B per lane
__device__ __forceinline__ void gl_lds16(const float* g, float* l) {
    __builtin_amdgcn_global_load_lds(
        (const __attribute__((address_space(1))) void*)g,
        (__attribute__((address_space(3))) void*)l, 16, 0, 0);
}

__device__ __forceinline__ float dot48(const float* A, const float* Bp) {
    const float4* a = reinterpret_cast<const float4*>(A);
    const float4* b4 = reinterpret_cast<const float4*>(Bp);
    float4 acc = {0.f, 0.f, 0.f, 0.f};
#pragma unroll
    for (int i = 0; i < 12; ++i) {
        float4 x = a[i], y = b4[i];
        acc.x = fmaf(x.x, y.x, acc.x); acc.y = fmaf(x.y, y.y, acc.y);
        acc.z = fmaf(x.z, y.z, acc.z); acc.w = fmaf(x.w, y.w, acc.w);
    }
    return (acc.x + acc.y) + (acc.z + acc.w);
}
__device__ __forceinline__ float dot24(const float* A, const float* Bp) {
    const float4* a = reinterpret_cast<const float4*>(A);
    const float4* b4 = reinterpret_cast<const float4*>(Bp);
    float4 acc = {0.f, 0.f, 0.f, 0.f};
#pragma unroll
    for (int i = 0; i < 6; ++i) {
        float4 x = a[i], y = b4[i];
        acc.x = fmaf(x.x, y.x, acc.x); acc.y = fmaf(x.y, y.y, acc.y);
        acc.z = fmaf(x.z, y.z, acc.z); acc.w = fmaf(x.w, y.w, acc.w);
    }
    return (acc.x + acc.y) + (acc.z + acc.w);
}

// ---------------------------------------------------------------------------
// Kernel 1: ssum / qsum
// ---------------------------------------------------------------------------
__global__ __launch_bounds__(128) void ssum_kernel(
    const int* __restrict__ story, const int* __restrict__ query,
    const float* __restrict__ we, const float* __restrict__ pe,
    float* __restrict__ ssum, float* __restrict__ qsum)
{
    int i = blockIdx.x;
    int c = threadIdx.x;
    const int* idxp;
    float* outp;
    if (i < B_ * S_) {
        idxp = story + (size_t)i * W_;
        outp = ssum + (size_t)i * SYM_;
    } else {
        int b = i - B_ * S_;
        idxp = query + (size_t)b * W_;
        outp = qsum + (size_t)b * SYM_;
    }
    float acc = 0.f;
#pragma unroll
    for (int w = 0; w < W_; ++w) {
        int id = idxp[w];
        acc = fmaf(we[(size_t)id * SYM_ + c], pe[w * SYM_ + c], acc);
    }
    outp[c] = acc;
}

// ---------------------------------------------------------------------------
// Kernel 2 (r21): exact r18 mlp core (W1 3-slot LDS ring via global_load_lds,
// counted vmcnt(2) + raw s_barrier, x via wave-uniform s_loads, TM=24),
// with BOTH launches merged into one grid (256, 9):
//   y in [0,5): story heads over ssum (x-blocks 0..255, M=6144)
//   y in [5,9): query heads over qsum (x-blocks 0..5, M=128, store-guarded;
//               OOB x reads land in mapped workspace - harmless)
// Query blocks hide under the 1280 story blocks; one launch removed.
// ---------------------------------------------------------------------------
template<int NQ>
__device__ __forceinline__ void mlp_layer2(
    int t, int row0, int M, const float4* hs4, const float* __restrict__ W2,
    const float* __restrict__ b2, float* __restrict__ out)
{
    const float4* W2_4 = reinterpret_cast<const float4*>(W2);  // [256][NQ]
    for (int idx = t; idx < TMV * NQ; idx += 256) {
        int row = idx / NQ, q = idx - row * NQ;
        float4 cw0 = W2_4[0 * NQ + q];
        float4 cw1 = W2_4[1 * NQ + q];
        float4 cw2 = W2_4[2 * NQ + q];
        float4 cw3 = W2_4[3 * NQ + q];
        float4 a = {0, 0, 0, 0};
#pragma unroll 1
        for (int k4 = 0; k4 < H_ / 4 - 1; ++k4) {
            float4 nw0 = W2_4[(size_t)(4 * k4 + 4) * NQ + q];
            float4 nw1 = W2_4[(size_t)(4 * k4 + 5) * NQ + q];
            float4 nw2 = W2_4[(size_t)(4 * k4 + 6) * NQ + q];
            float4 nw3 = W2_4[(size_t)(4 * k4 + 7) * NQ + q];
            float4 h = hs4[row * 65 + k4];
            a = fma4(h.x, cw0, fma4(h.y, cw1, fma4(h.z, cw2, fma4(h.w, cw3, a))));
            cw0 = nw0; cw1 = nw1; cw2 = nw2; cw3 = nw3;
        }
        {
            float4 h = hs4[row * 65 + (H_ / 4 - 1)];
            a = fma4(h.x, cw0, fma4(h.y, cw1, fma4(h.z, cw2, fma4(h.w, cw3, a))));
        }
        if (row0 + row < M) {
            float4 bv = reinterpret_cast<const float4*>(b2)[q];
            float4 o;
            o.x = tanhf(a.x + bv.x); o.y = tanhf(a.y + bv.y);
            o.z = tanhf(a.z + bv.z); o.w = tanhf(a.w + bv.w);
            reinterpret_cast<float4*>(out + (size_t)(row0 + row) * (NQ * 4))[q] = o;
        }
    }
}

__global__ __launch_bounds__(256) void mlp_kernel(
    const float* __restrict__ xs, const float* __restrict__ xq,
    const float* __restrict__ ue_W1, const float* __restrict__ ue_b1,
    const float* __restrict__ ue_W2, const float* __restrict__ ue_b2,
    const float* __restrict__ ur_W1, const float* __restrict__ ur_b1,
    const float* __restrict__ ur_W2, const float* __restrict__ ur_b2,
    const float* __restrict__ ie_W1, const float* __restrict__ ie_b1,
    const float* __restrict__ ie_W2, const float* __restrict__ ie_b2,
    const float* __restrict__ ir_W1, const float* __restrict__ ir_b1,
    const float* __restrict__ ir_W2, const float* __restrict__ ir_b2,
    float* __restrict__ eout,   // [2][6144][48]
    float* __restrict__ rout,   // [3][6144][24]
    float* __restrict__ qe1,    // [128][48]
    float* __restrict__ qrr)    // [3][128][24]
{
    const int y = blockIdx.y;
    const float* x;
    int M;
    const float *W1, *b1, *W2, *b2;
    float* out;
    int OUT;
    if (y < 5) {
        x = xs; M = B_ * S_;
        if (y < 2) {
            W1 = ue_W1 + (size_t)y * SYM_ * H_;
            b1 = ue_b1 + (size_t)y * H_;
            W2 = ue_W2 + (size_t)y * H_ * E_;
            b2 = ue_b2 + (size_t)y * E_;
            out = eout + (size_t)y * M * E_;
            OUT = E_;
        } else {
            int mr = y - 2;
            W1 = ur_W1 + (size_t)mr * SYM_ * H_;
            b1 = ur_b1 + (size_t)mr * H_;
            W2 = ur_W2 + (size_t)mr * H_ * R_;
            b2 = ur_b2 + (size_t)mr * R_;
            out = rout + (size_t)mr * M * R_;
            OUT = R_;
        }
    } else {
        if (blockIdx.x >= 6) return;      // query needs only 6 x-blocks
        x = xq; M = B_;
        int qy = y - 5;
        if (qy == 0) {
            W1 = ie_W1; b1 = ie_b1; W2 = ie_W2; b2 = ie_b2;
            out = qe1; OUT = E_;
        } else {
            int mr = qy - 1;
            W1 = ir_W1 + (size_t)mr * SYM_ * H_;
            b1 = ir_b1 + (size_t)mr * H_;
            W2 = ir_W2 + (size_t)mr * H_ * R_;
            b2 = ir_b2 + (size_t)mr * R_;
            out = qrr + (size_t)mr * B_ * R_;
            OUT = R_;
        }
    }
    const int row0 = blockIdx.x * TMV;

    const int t = threadIdx.x;
    const int wv = t >> 6;      // wave owns rows 6wv..6wv+5
    const int l = t & 63;       // lane = col-quad

    __shared__ __align__(16) float4 pool4[TMV * 65];  // 25 KB >= ring 24 KB
    float* wlds = reinterpret_cast<float*>(pool4);

    // wave-uniform x row base -> SGPR -> x reads are s_loads
    const int xoff = __builtin_amdgcn_readfirstlane((row0 + ROWS * wv) * SYM_);
    const float* xw = x + xoff;

#define STAGE(c) { \
    const float* gsrc = W1 + (c) * 2048 + t * 4; \
    float* dst = wlds + ((c) % 3) * 2048 + wv * 256; \
    gl_lds16(gsrc, dst); \
    gl_lds16(gsrc + 1024, dst + 1024); }

#define CHUNK_COMPUTE(c_) { \
    const float* wl = wlds + ((c_) % 3) * 2048; \
    const float* xc = xw + (c_) * 8; \
    _Pragma("unroll") \
    for (int k = 0; k < 8; ++k) { \
        f32x4 w4 = *reinterpret_cast<const f32x4*>(wl + k * 256 + l * 4); \
        A0 = fmabc(xc[0 * SYM_ + k], w4, A0); \
        A1 = fmabc(xc[1 * SYM_ + k], w4, A1); \
        A2 = fmabc(xc[2 * SYM_ + k], w4, A2); \
        A3 = fmabc(xc[3 * SYM_ + k], w4, A3); \
        A4 = fmabc(xc[4 * SYM_ + k], w4, A4); \
        A5 = fmabc(xc[5 * SYM_ + k], w4, A5); \
    } }

    f32x4 A0 = {0.f, 0.f, 0.f, 0.f};
    f32x4 A1 = A0, A2 = A0, A3 = A0, A4 = A0, A5 = A0;

    STAGE(0)
    STAGE(1)

#pragma unroll 1
    for (int c = 0; c < 15; ++c) {
        asm volatile("s_waitcnt vmcnt(2)" ::: "memory");
        __builtin_amdgcn_s_barrier();
        if (c + 2 < 16) STAGE(c + 2)
        CHUNK_COMPUTE(c)
    }
    asm volatile("s_waitcnt vmcnt(0)" ::: "memory");
    __builtin_amdgcn_s_barrier();
    CHUNK_COMPUTE(15)
#undef CHUNK_COMPUTE
#undef STAGE

    __syncthreads();   // ring reads done before h overwrites pool

    {
        float4 bb = reinterpret_cast<const float4*>(b1)[l];
        float4 v;
#define H1ROW(i, AR) \
        v.x = tanhf(AR[0] + bb.x); v.y = tanhf(AR[1] + bb.y); \
        v.z = tanhf(AR[2] + bb.z); v.w = tanhf(AR[3] + bb.w); \
        pool4[(ROWS * wv + (i)) * 65 + l] = v;
        H1ROW(0, A0) H1ROW(1, A1) H1ROW(2, A2)
        H1ROW(3, A3) H1ROW(4, A4) H1ROW(5, A5)
#undef H1ROW
    }
    __syncthreads();

    if (OUT == E_) mlp_layer2<12>(t, row0, M, pool4, W2, b2, out);
    else           mlp_layer2<6>(t, row0, M, pool4, W2, b2, out);
}

// ---------------------------------------------------------------------------
// Kernel 3: FUSED gram + rec (unchanged from r18).
// ---------------------------------------------------------------------------
__global__ __launch_bounds__(512) void gramrec_kernel(
    const float* __restrict__ eg,   // [2][B][48][48]
    const float* __restrict__ rg,   // [3][B][48][24]
    const float* __restrict__ qe1,  // [B][48]
    const float* __restrict__ qrr,  // [3][B][24]
    float* __restrict__ qg,         // [B][544]
    float* __restrict__ abcg)       // [B][3][48][48]
{
    const int b = blockIdx.x;
    const int half = blockIdx.y;
    const int f0 = half * 24;
    const int t = threadIdx.x;

    __shared__ __align__(16) float eL[2][48][52];
    __shared__ __align__(16) float rL[3][48][28];
    __shared__ __align__(16) float KL[1128 * 12];
    __shared__ float acc[3][48][24];
    __shared__ float abc[3][48][24];

    for (int i = t; i < 2 * 2304; i += 512) {
        int x = i / 2304, rem = i - x * 2304;
        eL[x][rem / 48][rem % 48] = eg[(size_t)x * B_ * 2304 + (size_t)b * 2304 + rem];
    }
    for (int i = t; i < 3 * 1152; i += 512) {
        int x = i / 1152, rem = i - x * 1152;
        rL[x][rem / 24][rem % 24] = rg[(size_t)x * B_ * 1152 + (size_t)b * 1152 + rem];
    }
    for (int i = t; i < 3 * 48 * 24; i += 512) ((float*)acc)[i] = 0.f;
    __syncthreads();

    for (int k = t; k < 1128; k += 512) {
        int s2 = (int)((1.0f + sqrtf(1.0f + 8.0f * (float)k)) * 0.5f);
        while (s2 * (s2 - 1) / 2 > k) --s2;
        while ((s2 + 1) * s2 / 2 <= k) ++s2;
        int sp = k - s2 * (s2 - 1) / 2;

        float G11 = dot48(&eL[0][s2][0], &eL[0][sp][0]);
        float G12 = dot48(&eL[0][s2][0], &eL[1][sp][0]);
        float G21 = dot48(&eL[1][s2][0], &eL[0][sp][0]);
        float G22 = dot48(&eL[1][s2][0], &eL[1][sp][0]);
        float R11 = dot24(&rL[0][s2][0], &rL[0][sp][0]);
        float R12 = dot24(&rL[0][s2][0], &rL[1][sp][0]);
        float R13 = dot24(&rL[0][s2][0], &rL[2][sp][0]);
        float R21 = dot24(&rL[1][s2][0], &rL[0][sp][0]);
        float R22 = dot24(&rL[1][s2][0], &rL[1][sp][0]);
        float R23 = dot24(&rL[1][s2][0], &rL[2][sp][0]);
        float R31 = dot24(&rL[2][s2][0], &rL[0][sp][0]);
        float R32 = dot24(&rL[2][s2][0], &rL[1][sp][0]);
        float R33 = dot24(&rL[2][s2][0], &rL[2][sp][0]);

        float* kp = KL + (size_t)k * 12;
        float4 o0 = {G11 * R11, G11 * R12, G12 * R13, G11 * R21};
        float4 o1 = {G11 * R22, G12 * R23, G21 * R31, G21 * R32};
        *reinterpret_cast<float4*>(kp)     = o0;
        *reinterpret_cast<float4*>(kp + 4) = o1;
        kp[8] = G22 * R33;
    }

    if (half == 0) {
        float* dst = qg + (size_t)b * 544;
        for (int j = t; j < 528; j += 512) {
            if (j < 96) {
                int x = j / 48, sp = j % 48;
                const float* q = qe1 + b * 48;
                const float* v = &eL[x][sp][0];
                float a = 0.f;
#pragma unroll
                for (int kk = 0; kk < 48; ++kk) a = fmaf(q[kk], v[kk], a);
                dst[j] = a;
            } else {
                int jj = j - 96;
                int c = jj / 144;
                int rem = jj - c * 144;
                int rj = rem / 48, sp = rem % 48;
                const float* q = qrr + ((size_t)c * B_ + b) * 24;
                const float* v = &rL[rj][sp][0];
                float a = 0.f;
#pragma unroll
                for (int kk = 0; kk < 24; ++kk) a = fmaf(q[kk], v[kk], a);
                dst[j] = a;
            }
        }
    }
    __syncthreads();

    for (int s = 0; s < 48; ++s) {
        if (t < 24) {
            float w = acc[0][s][t], m = acc[1][s][t], bh = acc[2][s][t];
            abc[0][s][t] = eL[1][s][f0 + t] - w;
            abc[1][s][t] = w - m;
            abc[2][s][t] = eL[0][s][f0 + t] - bh;
        }
        __syncthreads();
        const int items = (47 - s) * 24;
        for (int idx = t; idx < items; idx += 512) {
            int d = idx / 24;
            int fl = idx - d * 24;
            int s2 = s + 1 + d;
            const float* kp = KL + (size_t)(s2 * (s2 - 1) / 2 + s) * 12;
            float4 k0 = *reinterpret_cast<const float4*>(kp);
            float4 k1 = *reinterpret_cast<const float4*>(kp + 4);
            float  k8 = kp[8];
            float av = abc[0][s][fl], bv = abc[1][s][fl], cv = abc[2][s][fl];
            acc[0][s2][fl] = fmaf(k0.x, av, fmaf(k0.y, bv, fmaf(k0.z, cv, acc[0][s2][fl])));
            acc[1][s2][fl] = fmaf(k0.w, av, fmaf(k1.x, bv, fmaf(k1.y, cv, acc[1][s2][fl])));
            acc[2][s2][fl] = fmaf(k1.z, av, fmaf(k1.w, bv, fmaf(k8,   cv, acc[2][s2][fl])));
        }
        __syncthreads();
    }
    for (int i = t; i < 3 * 48 * 24; i += 512) {
        int x = i / (48 * 24);
        int rem = i - x * 48 * 24;
        int s = rem / 24, fl = rem % 24;
        abcg[(size_t)b * 6912 + (size_t)x * 2304 + s * 48 + f0 + fl] = abc[x][s][fl];
    }
}

// ---------------------------------------------------------------------------
// Kernel 4: inference. Contraction phase parallelized over 192 threads
// (f = t%48, g = t/48 < 4 owns sp range [12g,12g+12)), LDS-reduced.
// ---------------------------------------------------------------------------
__global__ __launch_bounds__(256) void infer2_kernel(
    const float* __restrict__ abcg, const float* __restrict__ eg,
    const float* __restrict__ qgg,
    const float* __restrict__ ln_gain, const float* __restrict__ ln_bias,
    float* __restrict__ isum)
{
    const int b = blockIdx.x;
    const int t = threadIdx.x;
    __shared__ float abc[3][48][48];
    __shared__ __align__(16) float eL[2][48][52];
    __shared__ float qgL[544];
    __shared__ float alpha[3][48];
    __shared__ float gtmp[2][48];
    __shared__ float part2[4][48];
    __shared__ float cur[48], xv[48], acc3[48];

    for (int i = t; i < 6912; i += 256) ((float*)abc)[i] = abcg[(size_t)b * 6912 + i];
    for (int i = t; i < 2 * 2304; i += 256) {
        int x = i / 2304, rem = i - x * 2304;
        eL[x][rem / 48][rem % 48] = eg[(size_t)x * B_ * 2304 + (size_t)b * 2304 + rem];
    }
    for (int i = t; i < 544; i += 256) qgL[i] = qgg[(size_t)b * 544 + i];
    if (t < 48) acc3[t] = 0.f;
    __syncthreads();

    for (int c = 0; c < 3; ++c) {
        if (c > 0) {
            for (int j = t; j < 96; j += 256) {
                int x = j / 48, sp = j % 48;
                const float* v = &eL[x][sp][0];
                float a = 0.f;
#pragma unroll
                for (int kk = 0; kk < 48; ++kk) a = fmaf(cur[kk], v[kk], a);
                gtmp[x][sp] = a;
            }
            __syncthreads();
        }
        if (t < 48) {
            float g1 = (c == 0) ? qgL[t] : gtmp[0][t];
            float g2 = (c == 0) ? qgL[48 + t] : gtmp[1][t];
            alpha[0][t] = g1 * qgL[96 + c * 144 + t];
            alpha[1][t] = g1 * qgL[96 + c * 144 + 48 + t];
            alpha[2][t] = g2 * qgL[96 + c * 144 + 96 + t];
        }
        __syncthreads();
        if (t < 192) {
            int f = t % 48, g = t / 48;
            float p = 0.f;
#pragma unroll
            for (int k = 0; k < 12; ++k) {
                int sp = 12 * g + k;
                p = fmaf(alpha[0][sp], abc[0][sp][f],
                    fmaf(alpha[1][sp], abc[1][sp][f],
                    fmaf(alpha[2][sp], abc[2][sp][f], p)));
            }
            part2[g][f] = p;
        }
        __syncthreads();
        if (t < 48) {
            xv[t] = (part2[0][t] + part2[1][t]) + (part2[2][t] + part2[3][t]);
        }
        __syncthreads();
        if (t < 48) {
            float mu = 0.f;
#pragma unroll
            for (int jj = 0; jj < 48; ++jj) mu += xv[jj];
            mu *= (1.f / 48.f);
            float var = 0.f;
#pragma unroll
            for (int jj = 0; jj < 48; ++jj) { float d = xv[jj] - mu; var = fmaf(d, d, var); }
            var *= (1.f / 48.f);
            float inv = 1.f / sqrtf(var + 1e-6f);
            float o = ln_gain[c * 48 + t] * (xv[t] - mu) * inv + ln_bias[c * 48 + t];
            cur[t] = o;
            acc3[t] += o;
        }
        __syncthreads();
    }
    if (t < 48) isum[b * 48 + t] = acc3[t];
}

// ---------------------------------------------------------------------------
// Kernel 5: logits[b,v] = sum_e isum[b,e] * Z[e,v]
// ---------------------------------------------------------------------------
__global__ __launch_bounds__(256) void logits_kernel(
    const float* __restrict__ isum,
    const float* __restrict__ Z,
    float* __restrict__ out)
{
    int v = blockIdx.x * 256 + threadIdx.x;
    int b0 = blockIdx.y * (B_ / 4);
    float z[E_];
#pragma unroll
    for (int e = 0; e < E_; ++e) z[e] = Z[(size_t)e * V_ + v];
    for (int b = b0; b < b0 + B_ / 4; ++b) {
        float a = 0.f;
#pragma unroll
        for (int e = 0; e < E_; ++e) a = fmaf(isum[b * 48 + e], z[e], a);
        out[(size_t)b * V_ + v] = a;
    }
}

// ---------------------------------------------------------------------------
extern "C" void kernel_launch(void* const* d_in, const int* in_sizes, int n_in,
                              void* d_out, int out_size, void* d_ws, size_t ws_size,
                              hipStream_t stream) {
    const int* story  = (const int*)d_in[0];
    const int* query  = (const int*)d_in[1];
    const float* we   = (const float*)d_in[2];
    const float* pe   = (const float*)d_in[3];
    const float* Z    = (const float*)d_in[4];
    const float* ue_W1 = (const float*)d_in[5];
    const float* ue_b1 = (const float*)d_in[6];
    const float* ue_W2 = (const float*)d_in[7];
    const float* ue_b2 = (const float*)d_in[8];
    const float* ur_W1 = (const float*)d_in[9];
    const float* ur_b1 = (const float*)d_in[10];
    const float* ur_W2 = (const float*)d_in[11];
    const float* ur_b2 = (const float*)d_in[12];
    const float* ie_W1 = (const float*)d_in[13];
    const float* ie_b1 = (const float*)d_in[14];
    const float* ie_W2 = (const float*)d_in[15];
    const float* ie_b2 = (const float*)d_in[16];
    const float* ir_W1 = (const float*)d_in[17];
    const float* ir_b1 = (const float*)d_in[18];
    const float* ir_W2 = (const float*)d_in[19];
    const float* ir_b2 = (const float*)d_in[20];
    const float* ln_g  = (const float*)d_in[21];
    const float* ln_b  = (const float*)d_in[22];
    float* out = (float*)d_out;

    float* ws = (float*)d_ws;
    float* ssum = ws;                                   // 786432
    float* qsum = ssum + (size_t)B_ * S_ * SYM_;        // 16384
    float* eout = qsum + (size_t)B_ * SYM_;             // 589824
    float* rout = eout + (size_t)2 * B_ * S_ * E_;      // 442368
    float* qe1  = rout + (size_t)3 * B_ * S_ * R_;      // 6144
    float* qrr  = qe1 + (size_t)B_ * E_;                // 9216
    float* abcg = qrr + (size_t)3 * B_ * R_;            // 884736
    float* qg   = abcg + (size_t)B_ * 6912;             // 69632
    float* isum = qg + (size_t)B_ * 544;                // 6144

    ssum_kernel<<<B_ * S_ + B_, 128, 0, stream>>>(story, query, we, pe, ssum, qsum);

    // merged story + query MLPs: grid (256, 9); query heads use x < 6
    mlp_kernel<<<dim3(256, 9), 256, 0, stream>>>(
        ssum, qsum,
        ue_W1, ue_b1, ue_W2, ue_b2,
        ur_W1, ur_b1, ur_W2, ur_b2,
        ie_W1, ie_b1, ie_W2, ie_b2,
        ir_W1, ir_b1, ir_W2, ir_b2,
        eout, rout, qe1, qrr);

    gramrec_kernel<<<dim3(B_, 2), 512, 0, stream>>>(eout, rout, qe1, qrr, qg, abcg);

    infer2_kernel<<<B_, 256, 0, stream>>>(abcg, eout, qg, ln_g, ln_b, isum);

    logits_kernel<<<dim3(V_ / 256, 4), 256, 0, stream>>>(isum, Z, out);
}